// Round 3
// baseline (41.664 us; speedup 1.0000x reference)
//
#include <hip/hip_runtime.h>
#include <math.h>

#define ATOMS 200

static __device__ __forceinline__ float3 f3(float x, float y, float z) {
    return make_float3(x, y, z);
}
static __device__ __forceinline__ float3 sub3(float3 a, float3 b) {
    return f3(a.x - b.x, a.y - b.y, a.z - b.z);
}
static __device__ __forceinline__ float dot3(float3 a, float3 b) {
    return a.x * b.x + a.y * b.y + a.z * b.z;
}
static __device__ __forceinline__ float3 cross3(float3 a, float3 b) {
    return f3(a.y * b.z - a.z * b.y,
              a.z * b.x - a.x * b.z,
              a.x * b.y - a.y * b.x);
}
// normalize with rsqrt + one Newton-Raphson step
static __device__ __forceinline__ float3 nrm3(float3 a) {
    float d = dot3(a, a);
    float r = rsqrtf(d);
    r = r * (1.5f - 0.5f * d * r * r);
    return f3(a.x * r, a.y * r, a.z * r);
}
static __device__ __forceinline__ float asin_clamped(float v) {
    return asinf(fminf(1.0f, fmaxf(-1.0f, v)));
}

// base(i) = number of (i',j) pairs with i' < i  (row i has m-i entries)
static __device__ __forceinline__ int row_base(int i, int m) {
    return i * m - (i * (i - 1)) / 2;
}

__global__ __launch_bounds__(256) void writhe_kernel(
    const float* __restrict__ xyz,
    float*       __restrict__ out,
    int S, int m /* = A-3: entries in row 0 */)
{
    __shared__ float sx[ATOMS * 3];

    const int f = blockIdx.y;
    const float* fx = xyz + (size_t)f * (ATOMS * 3);
    for (int t = threadIdx.x; t < ATOMS * 3; t += blockDim.x)
        sx[t] = fx[t];
    __syncthreads();

    const int s = blockIdx.x * blockDim.x + threadIdx.x;
    if (s >= S) return;

    // analytic triu_indices(n_starts, k=2) row-major inversion
    const double tm = 2.0 * (double)m + 1.0;
    int i = (int)(0.5 * (tm - sqrt(tm * tm - 8.0 * (double)s)));
    if (i < 0) i = 0;
    if (i > m - 1) i = m - 1;
    while (i < m - 1 && row_base(i + 1, m) <= s) ++i;
    while (i > 0 && row_base(i, m) > s) --i;
    const int j = i + 2 + (s - row_base(i, m));

    // atoms: [i, i+1, j, j+1]
    const float3 p0 = f3(sx[3 * i],     sx[3 * i + 1], sx[3 * i + 2]);
    const float3 p1 = f3(sx[3 * i + 3], sx[3 * i + 4], sx[3 * i + 5]);
    const float3 p2 = f3(sx[3 * j],     sx[3 * j + 1], sx[3 * j + 2]);
    const float3 p3 = f3(sx[3 * j + 3], sx[3 * j + 4], sx[3 * j + 5]);

    // disp (normalized): d0 = p2-p0, d1 = p3-p0, d2 = p2-p1, d3 = p3-p1
    const float3 d0 = nrm3(sub3(p2, p0));
    const float3 d1 = nrm3(sub3(p3, p0));
    const float3 d2 = nrm3(sub3(p2, p1));
    const float3 d3 = nrm3(sub3(p3, p1));

    // crosses (normalized): c0 = d0 x d1, c1 = d1 x d3, c3 = d2 x d0.
    // c2 = d3 x d2 is NOT needed: the reference's dots[2] = c2 . c2 = 1
    // (it gathers the second operand with idx_b again), so that term is
    // a constant asin(1) = pi/2.
    const float3 c0 = nrm3(cross3(d0, d1));
    const float3 c1 = nrm3(cross3(d1, d3));
    const float3 c3 = nrm3(cross3(d2, d0));

    // dots per reference: [c0.c1, c1.c3, c2.c2 (=1), c3.c0]
    const float half_pi = 1.5707963267948966f;
    const float omega =
        asin_clamped(dot3(c0, c1)) +
        asin_clamped(dot3(c1, c3)) +
        half_pi +
        asin_clamped(dot3(c3, c0));

    // sign( ((p3-p2) x (p1-p0)) . d0 )
    const float sv = dot3(cross3(sub3(p3, p2), sub3(p1, p0)), d0);
    const float sgn = (sv > 0.0f) ? 1.0f : ((sv < 0.0f) ? -1.0f : 0.0f);

    const float inv2pi = 0.15915494309189535f;  // 1/(2*pi)
    out[(size_t)f * S + s] = omega * sgn * inv2pi;
}

extern "C" void kernel_launch(void* const* d_in, const int* in_sizes, int n_in,
                              void* d_out, int out_size, void* d_ws, size_t ws_size,
                              hipStream_t stream)
{
    const float* xyz = (const float*)d_in[0];
    float*       out = (float*)d_out;

    const int F = in_sizes[0] / (ATOMS * 3);
    const int S = out_size / F;              // = (A-2)(A-3)/2
    // m = entries in triu row 0 = A - 3; recover from S: m(m+1)/2 = S
    const int m = (int)((-1.0 + sqrt(1.0 + 8.0 * (double)S)) * 0.5 + 0.5);

    dim3 grid((S + 255) / 256, F);
    writhe_kernel<<<grid, 256, 0, stream>>>(xyz, out, S, m);
}

// Round 4
// 26.566 us; speedup vs baseline: 1.5683x; 1.5683x over previous
//
#include <hip/hip_runtime.h>
#include <math.h>

#define ATOMS 200

static __device__ __forceinline__ float3 f3(float x, float y, float z) {
    return make_float3(x, y, z);
}
static __device__ __forceinline__ float3 sub3(float3 a, float3 b) {
    return f3(a.x - b.x, a.y - b.y, a.z - b.z);
}
static __device__ __forceinline__ float dot3(float3 a, float3 b) {
    return fmaf(a.x, b.x, fmaf(a.y, b.y, a.z * b.z));
}
static __device__ __forceinline__ float3 cross3(float3 a, float3 b) {
    return f3(fmaf(a.y, b.z, -a.z * b.y),
              fmaf(a.z, b.x, -a.x * b.z),
              fmaf(a.x, b.y, -a.y * b.x));
}

// asin via A&S 4.4.45 (Hastings): abs err <= 6.8e-5 rad, ~9 VALU.
// asin(x) = sign(x) * (pi/2 - sqrt(1-|x|) * (a0 + a1|x| + a2|x|^2 + a3|x|^3))
// Input clamped to [-1,1] (matches reference's jnp.clip before arcsin).
static __device__ __forceinline__ float asin_fast(float x) {
    float a = fminf(fabsf(x), 1.0f);          // clamp (also absorbs >1 fp slop)
    float t = __builtin_amdgcn_sqrtf(1.0f - a);
    float p = fmaf(a, -0.0187293f, 0.0742610f);
    p = fmaf(a, p, -0.2121144f);
    p = fmaf(a, p, 1.5707288f);
    float r = fmaf(-t, p, 1.5707963267948966f);
    return copysignf(r, x);
}

// base(i) = number of (i',j) pairs with i' < i  (row i has m-i entries)
static __device__ __forceinline__ int row_base(int i, int m) {
    return i * m - (i * (i - 1)) / 2;
}

__global__ __launch_bounds__(256) void writhe_kernel(
    const float* __restrict__ xyz,
    float*       __restrict__ out,
    int S, int m /* = A-3 */)
{
    __shared__ float sx[ATOMS * 3];

    const int f = blockIdx.y;
    const float* fx = xyz + (size_t)f * (ATOMS * 3);
    for (int t = threadIdx.x; t < ATOMS * 3; t += blockDim.x)
        sx[t] = fx[t];
    __syncthreads();

    const int s = blockIdx.x * blockDim.x + threadIdx.x;
    if (s >= S) return;

    // analytic triu_indices(n_starts, k=2) inversion, fp32 (disc < 2^24 exact)
    const float tm = 2.0f * (float)m + 1.0f;
    const float disc = fmaf(tm, tm, -8.0f * (float)s);
    int i = (int)(0.5f * (tm - __builtin_amdgcn_sqrtf(disc)));
    i = max(0, min(i, m - 1));
    while (i < m - 1 && row_base(i + 1, m) <= s) ++i;
    while (i > 0 && row_base(i, m) > s) --i;
    const int j = i + 2 + (s - row_base(i, m));

    // atoms: [i, i+1, j, j+1]
    const float3 p0 = f3(sx[3 * i],     sx[3 * i + 1], sx[3 * i + 2]);
    const float3 p1 = f3(sx[3 * i + 3], sx[3 * i + 4], sx[3 * i + 5]);
    const float3 p2 = f3(sx[3 * j],     sx[3 * j + 1], sx[3 * j + 2]);
    const float3 p3 = f3(sx[3 * j + 3], sx[3 * j + 4], sx[3 * j + 5]);

    // Unnormalized displacements. The reference normalizes these, but
    // nnorm(cross(a,b)) and the sign term are invariant to positive
    // scaling of a,b — so the 4 normalizations are redundant.
    const float3 e0 = sub3(p2, p0);
    const float3 e1 = sub3(p3, p0);
    const float3 e2 = sub3(p2, p1);
    const float3 e3 = sub3(p3, p1);

    // Unnormalized crosses (c2 never needed: ref's dots[2] = c2.c2 = 1).
    const float3 u0 = cross3(e0, e1);
    const float3 u1 = cross3(e1, e3);
    const float3 u3 = cross3(e2, e0);

    // Normalize at the dot: c_a.c_b = (u_a.u_b) * rsqrt(|u_a|^2 |u_b|^2).
    const float n0 = dot3(u0, u0);
    const float n1 = dot3(u1, u1);
    const float n3 = dot3(u3, u3);

    const float d01 = dot3(u0, u1) * __builtin_amdgcn_rsqf(n0 * n1);
    const float d13 = dot3(u1, u3) * __builtin_amdgcn_rsqf(n1 * n3);
    const float d30 = dot3(u3, u0) * __builtin_amdgcn_rsqf(n3 * n0);

    const float half_pi = 1.5707963267948966f;
    const float omega = asin_fast(d01) + asin_fast(d13) + half_pi + asin_fast(d30);

    // sign( ((p3-p2) x (p1-p0)) . d0 )  ==  sign( -(e0 x e1) . e2 ) = sign(-u0.e2)
    const float sv = -dot3(u0, e2);
    const float sgn = (sv > 0.0f) ? 1.0f : ((sv < 0.0f) ? -1.0f : 0.0f);

    const float inv2pi = 0.15915494309189535f;  // 1/(2*pi)
    out[(size_t)f * S + s] = omega * sgn * inv2pi;
}

extern "C" void kernel_launch(void* const* d_in, const int* in_sizes, int n_in,
                              void* d_out, int out_size, void* d_ws, size_t ws_size,
                              hipStream_t stream)
{
    const float* xyz = (const float*)d_in[0];
    float*       out = (float*)d_out;

    const int F = in_sizes[0] / (ATOMS * 3);
    const int S = out_size / F;              // = (A-2)(A-3)/2
    const int m = (int)((-1.0 + sqrt(1.0 + 8.0 * (double)S)) * 0.5 + 0.5);

    dim3 grid((S + 255) / 256, F);
    writhe_kernel<<<grid, 256, 0, stream>>>(xyz, out, S, m);
}

// Round 5
// 25.617 us; speedup vs baseline: 1.6264x; 1.0370x over previous
//
#include <hip/hip_runtime.h>
#include <math.h>

#define ATOMS 200
#define W 4

static __device__ __forceinline__ float3 f3(float x, float y, float z) {
    return make_float3(x, y, z);
}
static __device__ __forceinline__ float3 sub3(float3 a, float3 b) {
    return f3(a.x - b.x, a.y - b.y, a.z - b.z);
}
static __device__ __forceinline__ float dot3(float3 a, float3 b) {
    return fmaf(a.x, b.x, fmaf(a.y, b.y, a.z * b.z));
}
static __device__ __forceinline__ float3 cross3(float3 a, float3 b) {
    return f3(fmaf(a.y, b.z, -a.z * b.y),
              fmaf(a.z, b.x, -a.x * b.z),
              fmaf(a.x, b.y, -a.y * b.x));
}
static __device__ __forceinline__ float3 neg3(float3 a) {
    return f3(-a.x, -a.y, -a.z);   // folds into consumer fma -src modifiers
}

// asin via A&S 4.4.45: abs err <= 6.8e-5 rad (threshold is 2e-2)
static __device__ __forceinline__ float asin_fast(float x) {
    float a = fminf(fabsf(x), 1.0f);
    float t = __builtin_amdgcn_sqrtf(1.0f - a);
    float p = fmaf(a, -0.0187293f, 0.0742610f);
    p = fmaf(a, p, -0.2121144f);
    p = fmaf(a, p, 1.5707288f);
    return copysignf(fmaf(-t, p, 1.5707963267948966f), x);
}

static __device__ __forceinline__ int row_base(int i, int m) {
    return i * m - (i * (i - 1)) / 2;
}

__global__ __launch_bounds__(256) void writhe_kernel(
    const float* __restrict__ xyz,
    float*       __restrict__ out,
    int S, int m /* = A-3 */)
{
    const int f = blockIdx.y;
    const float3* __restrict__ P =
        reinterpret_cast<const float3*>(xyz + (size_t)f * (ATOMS * 3));

    const int t = blockIdx.x * blockDim.x + threadIdx.x;
    const int s0 = t * W;
    if (s0 >= S) return;

    // analytic triu_indices(n_starts, k=2) inversion (disc < 2^24: exact fp32)
    const float tm = 2.0f * (float)m + 1.0f;
    const float disc = fmaf(tm, tm, -8.0f * (float)s0);
    int i = (int)(0.5f * (tm - __builtin_amdgcn_sqrtf(disc)));
    i = max(0, min(i, m - 1));
    while (i < m - 1 && row_base(i + 1, m) <= s0) ++i;
    while (i > 0 && row_base(i, m) > s0) --i;
    int j = i + 2 + (s0 - row_base(i, m));
    const int jmax = m + 1;

    // prefetch the sliding window (clamped; overfetch past row end is unused)
    const float3 q4 = P[min(j + 2, ATOMS - 1)];
    const float3 q5 = P[min(j + 3, ATOMS - 1)];
    const float3 q6 = P[min(j + 4, ATOMS - 1)];

    float3 p0 = P[i], p1 = P[i + 1], p2 = P[j], p3 = P[j + 1];
    float3 d0 = sub3(p2, p0), d2 = sub3(p2, p1);
    float3 u1p = f3(0.f, 0.f, 0.f);
    float  n1p = 0.f;
    bool rolled = false, crossed = false;

    float res0 = 0.f, res1 = 0.f, res2 = 0.f, res3 = 0.f;
    const float half_pi = 1.5707963267948966f;
    const float inv2pi  = 0.15915494309189535f;

    #pragma unroll
    for (int k = 0; k < W; ++k) {
        const float3 d1 = sub3(p3, p0), d3 = sub3(p3, p1);
        const float3 u0 = cross3(d0, d1);  const float n0 = dot3(u0, u0);
        const float3 u1 = cross3(d1, d3);  const float n1 = dot3(u1, u1);
        float3 u3; float n3;
        if (rolled) { u3 = neg3(u1p);      n3 = n1p; }          // u3(j) = -u1(j-1)
        else        { u3 = cross3(d2, d0); n3 = dot3(u3, u3); }

        const float d01 = dot3(u0, u1) * __builtin_amdgcn_rsqf(n0 * n1);
        const float d13 = dot3(u1, u3) * __builtin_amdgcn_rsqf(n1 * n3);
        const float d30 = dot3(u3, u0) * __builtin_amdgcn_rsqf(n3 * n0);

        const float omega =
            asin_fast(d01) + asin_fast(d13) + half_pi + asin_fast(d30);

        // sign( ((p3-p2) x (p1-p0)) . d0 ) == sign(-u0.d2)
        const float sv  = -dot3(u0, d2);
        const float sgn = (sv > 0.f) ? 1.f : ((sv < 0.f) ? -1.f : 0.f);
        const float r   = omega * sgn * inv2pi;
        if      (k == 0) res0 = r;
        else if (k == 1) res1 = r;
        else if (k == 2) res2 = r;
        else             res3 = r;

        if (k < W - 1 && s0 + k + 1 < S) {
            ++j;
            if (j > jmax) {                      // row switch (rare, divergent)
                ++i; j = i + 2;
                p0 = P[i]; p1 = P[i + 1]; p2 = P[j]; p3 = P[j + 1];
                d0 = sub3(p2, p0); d2 = sub3(p2, p1);
                rolled = false; crossed = true;
            } else {                             // roll along the row
                p2 = p3;
                if (crossed) p3 = P[j + 1];
                else         p3 = (k == 0) ? q4 : (k == 1) ? q5 : q6;
                d0 = d1; d2 = d3;
                u1p = u1; n1p = n1;
                rolled = true;
            }
        }
    }

    float* o = out + (size_t)f * S + s0;
    o[0] = res0;
    if (s0 + 1 < S) o[1] = res1;
    if (s0 + 2 < S) o[2] = res2;
    if (s0 + 3 < S) o[3] = res3;
}

extern "C" void kernel_launch(void* const* d_in, const int* in_sizes, int n_in,
                              void* d_out, int out_size, void* d_ws, size_t ws_size,
                              hipStream_t stream)
{
    const float* xyz = (const float*)d_in[0];
    float*       out = (float*)d_out;

    const int F = in_sizes[0] / (ATOMS * 3);
    const int S = out_size / F;              // = (A-2)(A-3)/2
    const int m = (int)((-1.0 + sqrt(1.0 + 8.0 * (double)S)) * 0.5 + 0.5);

    const int s_threads = (S + W - 1) / W;
    dim3 grid((s_threads + 255) / 256, F);
    writhe_kernel<<<grid, 256, 0, stream>>>(xyz, out, S, m);
}

// Round 6
// 22.691 us; speedup vs baseline: 1.8361x; 1.1289x over previous
//
#include <hip/hip_runtime.h>
#include <math.h>

#define ATOMS 200
#define W 4

static __device__ __forceinline__ float3 f3(float x, float y, float z) {
    return make_float3(x, y, z);
}
static __device__ __forceinline__ float3 sub3(float3 a, float3 b) {
    return f3(a.x - b.x, a.y - b.y, a.z - b.z);
}
static __device__ __forceinline__ float dot3(float3 a, float3 b) {
    return fmaf(a.x, b.x, fmaf(a.y, b.y, a.z * b.z));
}
static __device__ __forceinline__ float3 cross3(float3 a, float3 b) {
    return f3(fmaf(a.y, b.z, -a.z * b.y),
              fmaf(a.z, b.x, -a.x * b.z),
              fmaf(a.x, b.y, -a.y * b.x));
}
static __device__ __forceinline__ float3 neg3(float3 a) {
    return f3(-a.x, -a.y, -a.z);   // folds into consumer fma -src modifiers
}

// asin via A&S 4.4.45: abs err <= 6.8e-5 rad (threshold is 2e-2)
static __device__ __forceinline__ float asin_fast(float x) {
    float a = fminf(fabsf(x), 1.0f);
    float t = __builtin_amdgcn_sqrtf(1.0f - a);
    float p = fmaf(a, -0.0187293f, 0.0742610f);
    p = fmaf(a, p, -0.2121144f);
    p = fmaf(a, p, 1.5707288f);
    return copysignf(fmaf(-t, p, 1.5707963267948966f), x);
}

// C4(K) = sum_{k=1}^{K} ceil(k/4)  (monotone, increments by q+1)
static __device__ __host__ __forceinline__ int C4(int K) {
    int q = K >> 2, r = K & 3;
    return 2 * q * (q + 1) + r * (q + 1);
}

// shared core: given crosses u0,u1,u3 with reciprocal norms r0,r1,r3 and d2
struct St { float3 d1, d3, u1; float r1; };

static __device__ __forceinline__ float wr_term(
    float3 u0, float3 u1, float3 u3, float r0, float r1, float r3, float3 d2)
{
    const float d01 = dot3(u0, u1) * (r0 * r1);
    const float d13 = dot3(u1, u3) * (r1 * r3);
    const float d30 = dot3(u3, u0) * (r3 * r0);
    const float omega = asin_fast(d01) + asin_fast(d13)
                      + 1.5707963267948966f + asin_fast(d30);
    const float sv  = -dot3(u0, d2);
    const float sgn = (sv > 0.f) ? 1.f : ((sv < 0.f) ? -1.f : 0.f);
    return omega * sgn * 0.15915494309189535f;
}

static __device__ __forceinline__ float elem_full(
    float3 a0, float3 a1, float3 p2, float3 p3, St& st)
{
    const float3 d0 = sub3(p2, a0), d1 = sub3(p3, a0);
    const float3 d2 = sub3(p2, a1), d3 = sub3(p3, a1);
    const float3 u0 = cross3(d0, d1);
    const float3 u1 = cross3(d1, d3);
    const float3 u3 = cross3(d2, d0);
    const float r0 = __builtin_amdgcn_rsqf(dot3(u0, u0));
    const float r1 = __builtin_amdgcn_rsqf(dot3(u1, u1));
    const float r3 = __builtin_amdgcn_rsqf(dot3(u3, u3));
    st.d1 = d1; st.d3 = d3; st.u1 = u1; st.r1 = r1;
    return wr_term(u0, u1, u3, r0, r1, r3, d2);
}

// rolled: d0 <- d1_prev, d2 <- d3_prev, u3 <- -u1_prev, r3 <- r1_prev
static __device__ __forceinline__ float elem_roll(
    float3 a0, float3 a1, float3 p3, St& st)
{
    const float3 d0 = st.d1, d2 = st.d3;
    const float3 d1 = sub3(p3, a0), d3 = sub3(p3, a1);
    const float3 u0 = cross3(d0, d1);
    const float3 u1 = cross3(d1, d3);
    const float3 u3 = neg3(st.u1);
    const float r0 = __builtin_amdgcn_rsqf(dot3(u0, u0));
    const float r1 = __builtin_amdgcn_rsqf(dot3(u1, u1));
    const float r3 = st.r1;
    const float res = wr_term(u0, u1, u3, r0, r1, r3, d2);
    st.d1 = d1; st.d3 = d3; st.u1 = u1; st.r1 = r1;
    return res;
}

__global__ __launch_bounds__(256) void writhe_kernel(
    const float* __restrict__ xyz,
    float*       __restrict__ out,
    int S, int m /* = A-3 */, int CH /* = C4(m) chunks per frame */)
{
    const int f = blockIdx.y;
    const float3* __restrict__ P =
        reinterpret_cast<const float3*>(xyz + (size_t)f * (ATOMS * 3));

    const int g = blockIdx.x * blockDim.x + threadIdx.x;
    if (g >= CH) return;

    // row inversion: h = CH - g; K = minimal row-length with C4(K) >= h
    const int h = CH - g;                          // 1..CH
    int K = (int)(__builtin_amdgcn_sqrtf(fmaf(8.f, (float)h, 4.f)) - 2.f);
    K = max(1, min(K, m));
    while (K < m && C4(K) < h) ++K;
    while (K > 1 && C4(K - 1) >= h) --K;

    const int i    = m - K;                        // row (segment-1 start)
    const int c    = g - (CH - C4(K));             // chunk within row
    const int j0   = i + 2 + 4 * c;                // first j of this chunk
    const int nrem = min(W, K - 4 * c);            // valid elements (1..4)
    const int s0   = i * m - (i * (i - 1)) / 2 + 4 * c;  // element index

    // loads: segment-1 atoms + sliding j-window (clamped to valid range)
    const float3 a0 = P[i], a1 = P[i + 1];
    const float3 q0 = P[j0];
    const float3 q1 = P[j0 + 1];
    const float3 q2 = P[j0 + min(2, nrem)];
    const float3 q3 = P[j0 + min(3, nrem)];
    const float3 q4 = P[j0 + min(4, nrem)];

    St st;
    const float r0v = elem_full(a0, a1, q0, q1, st);
    const float r1v = elem_roll(a0, a1, q2, st);
    const float r2v = elem_roll(a0, a1, q3, st);
    const float r3v = elem_roll(a0, a1, q4, st);

    float* o = out + (size_t)f * S + s0;
    o[0] = r0v;
    if (nrem > 1) o[1] = r1v;
    if (nrem > 2) o[2] = r2v;
    if (nrem > 3) o[3] = r3v;
}

extern "C" void kernel_launch(void* const* d_in, const int* in_sizes, int n_in,
                              void* d_out, int out_size, void* d_ws, size_t ws_size,
                              hipStream_t stream)
{
    const float* xyz = (const float*)d_in[0];
    float*       out = (float*)d_out;

    const int F = in_sizes[0] / (ATOMS * 3);
    const int S = out_size / F;              // = (A-2)(A-3)/2
    const int m = (int)((-1.0 + sqrt(1.0 + 8.0 * (double)S)) * 0.5 + 0.5);

    // chunks per frame: sum over rows of ceil(rowlen/4)
    const int q = m >> 2, r = m & 3;
    const int CH = 2 * q * (q + 1) + r * (q + 1);

    dim3 grid((CH + 255) / 256, F);
    writhe_kernel<<<grid, 256, 0, stream>>>(xyz, out, S, m, CH);
}

// Round 7
// 21.633 us; speedup vs baseline: 1.9259x; 1.0489x over previous
//
#include <hip/hip_runtime.h>
#include <math.h>

#define ATOMS 200
#define W 4
#define FB 2   // frames per thread

static __device__ __forceinline__ float3 f3(float x, float y, float z) {
    return make_float3(x, y, z);
}
static __device__ __forceinline__ float3 sub3(float3 a, float3 b) {
    return f3(a.x - b.x, a.y - b.y, a.z - b.z);
}
static __device__ __forceinline__ float dot3(float3 a, float3 b) {
    return fmaf(a.x, b.x, fmaf(a.y, b.y, a.z * b.z));
}
static __device__ __forceinline__ float3 cross3(float3 a, float3 b) {
    return f3(fmaf(a.y, b.z, -a.z * b.y),
              fmaf(a.z, b.x, -a.x * b.z),
              fmaf(a.x, b.y, -a.y * b.x));
}
static __device__ __forceinline__ float3 neg3(float3 a) {
    return f3(-a.x, -a.y, -a.z);   // folds into consumer fma -src modifiers
}

// asin via A&S 4.4.45: abs err <= 6.8e-5 rad (threshold is 2e-2)
static __device__ __forceinline__ float asin_fast(float x) {
    float a = fminf(fabsf(x), 1.0f);
    float t = __builtin_amdgcn_sqrtf(1.0f - a);
    float p = fmaf(a, -0.0187293f, 0.0742610f);
    p = fmaf(a, p, -0.2121144f);
    p = fmaf(a, p, 1.5707288f);
    return copysignf(fmaf(-t, p, 1.5707963267948966f), x);
}

// C4(K) = sum_{k=1}^{K} ceil(k/4) = (q+1)(2q+r) for K = 4q+r
static __device__ __host__ __forceinline__ int C4(int K) {
    int q = K >> 2, r = K & 3;
    return (q + 1) * (2 * q + r);
}

struct St { float3 d1, d3, u1; float r1; };

static __device__ __forceinline__ float wr_term(
    float3 u0, float3 u1, float3 u3, float r0, float r1, float r3, float3 d2)
{
    const float d01 = dot3(u0, u1) * (r0 * r1);
    const float d13 = dot3(u1, u3) * (r1 * r3);
    const float d30 = dot3(u3, u0) * (r3 * r0);
    const float omega = asin_fast(d01) + asin_fast(d13)
                      + 1.5707963267948966f + asin_fast(d30);
    const float sv  = -dot3(u0, d2);
    const float sgn = (sv > 0.f) ? 1.f : ((sv < 0.f) ? -1.f : 0.f);
    return omega * sgn * 0.15915494309189535f;
}

static __device__ __forceinline__ float elem_full(
    float3 a0, float3 a1, float3 p2, float3 p3, St& st)
{
    const float3 d0 = sub3(p2, a0), d1 = sub3(p3, a0);
    const float3 d2 = sub3(p2, a1), d3 = sub3(p3, a1);
    const float3 u0 = cross3(d0, d1);
    const float3 u1 = cross3(d1, d3);
    const float3 u3 = cross3(d2, d0);
    const float r0 = __builtin_amdgcn_rsqf(dot3(u0, u0));
    const float r1 = __builtin_amdgcn_rsqf(dot3(u1, u1));
    const float r3 = __builtin_amdgcn_rsqf(dot3(u3, u3));
    st.d1 = d1; st.d3 = d3; st.u1 = u1; st.r1 = r1;
    return wr_term(u0, u1, u3, r0, r1, r3, d2);
}

// rolled: d0 <- d1_prev, d2 <- d3_prev, u3 <- -u1_prev, r3 <- r1_prev
static __device__ __forceinline__ float elem_roll(
    float3 a0, float3 a1, float3 p3, St& st)
{
    const float3 d0 = st.d1, d2 = st.d3;
    const float3 d1 = sub3(p3, a0), d3 = sub3(p3, a1);
    const float3 u0 = cross3(d0, d1);
    const float3 u1 = cross3(d1, d3);
    const float3 u3 = neg3(st.u1);
    const float r0 = __builtin_amdgcn_rsqf(dot3(u0, u0));
    const float r1 = __builtin_amdgcn_rsqf(dot3(u1, u1));
    const float r3 = st.r1;
    const float res = wr_term(u0, u1, u3, r0, r1, r3, d2);
    st.d1 = d1; st.d3 = d3; st.u1 = u1; st.r1 = r1;
    return res;
}

__global__ __launch_bounds__(256) void writhe_kernel(
    const float* __restrict__ xyz,
    float*       __restrict__ out,
    int S, int m /* = A-3 */, int CH /* chunks per frame */, int F)
{
    const int g = blockIdx.x * blockDim.x + threadIdx.x;
    if (g >= CH) return;
    const int f0 = blockIdx.y * FB;

    // branchless row inversion: h = CH - g; K = min row-length with C4(K) >= h.
    // sqrt guess error < 1 (C4 = smooth K^2/8 + K/2 + delta, delta in [0,0.5],
    // slope >= 3/4); +-1 fixup via flat selects, no divergent loops.
    const int h = CH - g;                          // 1..CH
    int K = (int)(__builtin_amdgcn_sqrtf(fmaf(8.f, (float)h, 4.f)) - 2.f);
    K = max(1, min(K, m));
    K += (int)(K < m && C4(K) < h);
    K += (int)(K < m && C4(K) < h);
    K -= (int)(K > 1 && C4(K - 1) >= h);

    const int i    = m - K;                        // row (segment-1 start)
    const int c    = g - (CH - C4(K));             // chunk within row
    const int j0   = i + 2 + 4 * c;                // first j of this chunk
    const int nrem = min(W, K - 4 * c);            // valid elements (1..4)
    const int s0   = i * m - (i * (i - 1)) / 2 + 4 * c;

    // window offsets (clamped to row end), shared across frames
    const int o2 = min(2, nrem), o3 = min(3, nrem), o4 = min(4, nrem);

    #pragma unroll
    for (int fb = 0; fb < FB; ++fb) {
        const int f = f0 + fb;
        if (f >= F) break;
        const float3* __restrict__ P =
            reinterpret_cast<const float3*>(xyz) + (size_t)f * ATOMS;

        const float3 a0 = P[i], a1 = P[i + 1];
        const float3 q0 = P[j0],      q1 = P[j0 + 1];
        const float3 q2 = P[j0 + o2], q3 = P[j0 + o3], q4 = P[j0 + o4];

        St st;
        const float r0v = elem_full(a0, a1, q0, q1, st);
        const float r1v = elem_roll(a0, a1, q2, st);
        const float r2v = elem_roll(a0, a1, q3, st);
        const float r3v = elem_roll(a0, a1, q4, st);

        float* o = out + (size_t)f * S + s0;
        o[0] = r0v;
        if (nrem > 1) o[1] = r1v;
        if (nrem > 2) o[2] = r2v;
        if (nrem > 3) o[3] = r3v;
    }
}

extern "C" void kernel_launch(void* const* d_in, const int* in_sizes, int n_in,
                              void* d_out, int out_size, void* d_ws, size_t ws_size,
                              hipStream_t stream)
{
    const float* xyz = (const float*)d_in[0];
    float*       out = (float*)d_out;

    const int F = in_sizes[0] / (ATOMS * 3);
    const int S = out_size / F;              // = (A-2)(A-3)/2
    const int m = (int)((-1.0 + sqrt(1.0 + 8.0 * (double)S)) * 0.5 + 0.5);

    const int q = m >> 2, r = m & 3;
    const int CH = (q + 1) * (2 * q + r);    // chunks per frame

    dim3 grid((CH + 255) / 256, (F + FB - 1) / FB);
    writhe_kernel<<<grid, 256, 0, stream>>>(xyz, out, S, m, CH, F);
}